// Round 9
// baseline (335.902 us; speedup 1.0000x reference)
//
#include <hip/hip_runtime.h>
#include <hip/hip_bf16.h>
#include <stdint.h>

#define DM 1024   // d_model
#define DD 512    // d (proj out / head dim)
#define BB 32     // batch
#define LL 1024   // seq len
#define SCALE 0.04419417382415922f  // 1/sqrt(512)
#define MAT ((size_t)BB * LL * DD)  // elems per q/k/v matrix

typedef float f32x4 __attribute__((ext_vector_type(4)));
typedef short bf16x8 __attribute__((ext_vector_type(8)));
typedef short bf16x4 __attribute__((ext_vector_type(4)));

__device__ inline unsigned short f2bf(float f) {
    union { float f; uint32_t u; } v; v.f = f;
    uint32_t r = v.u + 0x7fffu + ((v.u >> 16) & 1u);
    return (unsigned short)(r >> 16);
}

__device__ inline bf16x4 cvt4(f32x4 a, float s) {
    bf16x4 r;
    r[0] = (short)f2bf(a[0] * s);
    r[1] = (short)f2bf(a[1] * s);
    r[2] = (short)f2bf(a[2] * s);
    r[3] = (short)f2bf(a[3] * s);
    return r;
}

#define GLOAD_LDS16(gsrc, ldst) \
    __builtin_amdgcn_global_load_lds((const __attribute__((address_space(1))) unsigned int*)(gsrc), \
        (__attribute__((address_space(3))) unsigned int*)(ldst), 16, 0, 0)

// full-drain barrier (proj4's per-phase publish at epilogue)
__device__ inline void publish_barrier() {
    asm volatile("s_waitcnt vmcnt(0)" ::: "memory");
    __builtin_amdgcn_sched_barrier(0);
    __builtin_amdgcn_s_barrier();
    __builtin_amdgcn_sched_barrier(0);
}

// counted-vmcnt phase gates
__device__ inline void gate6() {
    asm volatile("s_waitcnt vmcnt(6)" ::: "memory");
    __builtin_amdgcn_sched_barrier(0);
    __builtin_amdgcn_s_barrier();
    __builtin_amdgcn_sched_barrier(0);
}
__device__ inline void gate4() {
    asm volatile("s_waitcnt vmcnt(4)" ::: "memory");
    __builtin_amdgcn_sched_barrier(0);
    __builtin_amdgcn_s_barrier();
    __builtin_amdgcn_sched_barrier(0);
}
__device__ inline void gate2() {
    asm volatile("s_waitcnt vmcnt(2)" ::: "memory");
    __builtin_amdgcn_sched_barrier(0);
    __builtin_amdgcn_s_barrier();
    __builtin_amdgcn_sched_barrier(0);
}
__device__ inline void gate0() {
    asm volatile("s_waitcnt vmcnt(0)" ::: "memory");
    __builtin_amdgcn_sched_barrier(0);
    __builtin_amdgcn_s_barrier();
    __builtin_amdgcn_sched_barrier(0);
}
__device__ inline void gateB() {
    __builtin_amdgcn_sched_barrier(0);
    __builtin_amdgcn_s_barrier();
    __builtin_amdgcn_sched_barrier(0);
}
// attn6: barA waits K only (own 8 K-loads oldest; 8 V-loads may fly)
__device__ inline void gate8() {
    asm volatile("s_waitcnt vmcnt(8)" ::: "memory");
    __builtin_amdgcn_sched_barrier(0);
    __builtin_amdgcn_s_barrier();
    __builtin_amdgcn_sched_barrier(0);
}

// ---------------------------------------------------------------------------
// Kernel 0a: cast x fp32 -> bf16 (dest: d_out reused as scratch; dead by attn)
// ---------------------------------------------------------------------------
__global__ __launch_bounds__(256) void cast_x(const float* __restrict__ x,
                                              unsigned short* __restrict__ xb)
{
    size_t idx = (size_t)blockIdx.x * 256 + threadIdx.x;
    size_t base = idx * 8;
    f32x4 a = *(const f32x4*)(x + base);
    f32x4 b = *(const f32x4*)(x + base + 4);
    bf16x4 lo = cvt4(a, 1.0f), hi = cvt4(b, 1.0f);
    bf16x8 o = {lo[0], lo[1], lo[2], lo[3], hi[0], hi[1], hi[2], hi[3]};
    *(bf16x8*)(xb + base) = o;
}

// ---------------------------------------------------------------------------
// Kernel 0b: cast Wq/Wk/Wv fp32 -> bf16 (Wq pre-scaled by 1/sqrt(D))
// ---------------------------------------------------------------------------
__global__ __launch_bounds__(256) void cast_w(const float* __restrict__ Wq,
                                              const float* __restrict__ Wk,
                                              const float* __restrict__ Wv,
                                              unsigned short* __restrict__ Wb)
{
    size_t idx = (size_t)blockIdx.x * 256 + threadIdx.x;   // 0..196607
    int o = (int)(idx >> 16);
    size_t rem = idx & 65535;
    const float* W = (o == 0) ? Wq : (o == 1) ? Wk : Wv;
    float s = (o == 0) ? SCALE : 1.0f;
    size_t base = rem * 8;
    f32x4 a = *(const f32x4*)(W + base);
    f32x4 b = *(const f32x4*)(W + base + 4);
    bf16x4 lo = cvt4(a, s), hi = cvt4(b, s);
    bf16x8 out = {lo[0], lo[1], lo[2], lo[3], hi[0], hi[1], hi[2], hi[3]};
    *(bf16x8*)(Wb + (size_t)o * 524288 + base) = out;
}

// ---------------------------------------------------------------------------
// Kernel 1: q/k/v projection v4 (unchanged from round 8 — 8-phase 256x256,
// counted vmcnt, ~90 us).
// ---------------------------------------------------------------------------
__global__ __launch_bounds__(512, 2) void qkv_proj4(
    const unsigned short* __restrict__ xb,   // [32768][1024] bf16
    const unsigned short* __restrict__ Wb,   // [3][512][1024] bf16 (q pre-scaled)
    const float* __restrict__ bq, const float* __restrict__ bk, const float* __restrict__ bv,
    unsigned short* __restrict__ qkv)
{
    __shared__ __align__(16) unsigned short AL[2][2][8192];  // [buf][half][128 rows x 128B]
    __shared__ __align__(16) unsigned short BL[2][2][8192];  // 128 KB total

    const int o = blockIdx.y;
    const float* bias = (o == 0) ? bq : (o == 1) ? bk : bv;
    const float wscale = (o == 0) ? SCALE : 1.0f;
    const unsigned short* W = Wb + (size_t)o * 524288;
    unsigned short* out = qkv + (size_t)o * MAT;

    int wg = blockIdx.x;                    // 256 blocks: XCD swizzle (8 x 32, bijective)
    wg = (wg & 7) * 32 + (wg >> 3);
    const int mt = wg >> 1, nt = wg & 1;
    const int rowbase = mt * 256;
    const int colbase = nt * 256;

    const int tid  = threadIdx.x;
    const int lane = tid & 63;
    const int w    = tid >> 6;              // 0..7
    const int wm   = w >> 2;                // 0..1
    const int wn   = w & 3;                 // 0..3
    const int l15  = lane & 15, l4 = lane >> 4;
    const int rxor = l15 & 7;

    const int r8   = lane >> 3;
    const int swch = (lane & 7) ^ r8;

    const char* xpanel = (const char*)(xb + (size_t)rowbase * DM);
    const char* wpanel = (const char*)(W  + (size_t)colbase * DM);

    #define STAGE_HALF(panel, T, H, slot) do {                                   \
        _Pragma("unroll")                                                        \
        for (int i2 = 0; i2 < 2; ++i2) {                                         \
            int grp = i2 * 8 + w;                                                \
            GLOAD_LDS16((panel) + ((size_t)((H) * 128 + grp * 8 + r8) * 2048)    \
                            + (size_t)(T) * 128 + swch * 16,                     \
                        (char*)(slot) + grp * 1024);                             \
        }                                                                        \
    } while (0)

    #define RDA(base, mf4, ks) (*(const bf16x8*)((base) + (wm * 64 + (mf4) * 16 + l15) * 128 \
                            + ((((ks) * 4 + l4) ^ rxor) << 4)))
    #define RDB(base, nfl, ks) (*(const bf16x8*)((base) + (wn * 32 + (nfl) * 16 + l15) * 128 \
                            + ((((ks) * 4 + l4) ^ rxor) << 4)))

    f32x4 acc[8][4];
    #pragma unroll
    for (int i = 0; i < 8; ++i)
        #pragma unroll
        for (int j = 0; j < 4; ++j)
            acc[i][j] = (f32x4){0.f, 0.f, 0.f, 0.f};

    bf16x8 aF[4][2], bF[4][2];

    STAGE_HALF(xpanel, 0, 0, &AL[0][0][0]);   // A0
    STAGE_HALF(wpanel, 0, 0, &BL[0][0][0]);   // B0
    STAGE_HALF(wpanel, 0, 1, &BL[0][1][0]);   // B1
    STAGE_HALF(xpanel, 0, 1, &AL[0][1][0]);   // A1

    for (int t = 0; t < 16; ++t) {
        const int c = t & 1, cn = c ^ 1;
        const char* A0b = (const char*)&AL[c][0][0];
        const char* A1b = (const char*)&AL[c][1][0];
        const char* B0b = (const char*)&BL[c][0][0];
        const char* B1b = (const char*)&BL[c][1][0];
        const bool st = (t < 15);

        // ---- phase 0: (A0,B0) ----
        if (st) { STAGE_HALF(xpanel, t + 1, 0, &AL[cn][0][0]); gate6(); } else gate4();
        #pragma unroll
        for (int ks = 0; ks < 2; ++ks) {
            #pragma unroll
            for (int mf = 0; mf < 4; ++mf) aF[mf][ks] = RDA(A0b, mf, ks);
            bF[0][ks] = RDB(B0b, 0, ks);
            bF[1][ks] = RDB(B0b, 1, ks);
        }
        #pragma unroll
        for (int ks = 0; ks < 2; ++ks)
            #pragma unroll
            for (int nf = 0; nf < 2; ++nf)
                #pragma unroll
                for (int mf = 0; mf < 4; ++mf)
                    acc[mf][nf] = __builtin_amdgcn_mfma_f32_16x16x32_bf16(aF[mf][ks], bF[nf][ks], acc[mf][nf], 0, 0, 0);

        // ---- phase 1: (A0,B1) ----
        if (st) { STAGE_HALF(wpanel, t + 1, 0, &BL[cn][0][0]); gate6(); } else gate2();
        #pragma unroll
        for (int ks = 0; ks < 2; ++ks) {
            bF[2][ks] = RDB(B1b, 0, ks);
            bF[3][ks] = RDB(B1b, 1, ks);
        }
        #pragma unroll
        for (int ks = 0; ks < 2; ++ks)
            #pragma unroll
            for (int nf = 0; nf < 2; ++nf)
                #pragma unroll
                for (int mf = 0; mf < 4; ++mf)
                    acc[mf][2 + nf] = __builtin_amdgcn_mfma_f32_16x16x32_bf16(aF[mf][ks], bF[2 + nf][ks], acc[mf][2 + nf], 0, 0, 0);

        // ---- phase 2: (A1,B0) ----
        if (st) { STAGE_HALF(wpanel, t + 1, 1, &BL[cn][1][0]); gate6(); } else gate0();
        #pragma unroll
        for (int ks = 0; ks < 2; ++ks)
            #pragma unroll
            for (int mf = 0; mf < 4; ++mf) aF[mf][ks] = RDA(A1b, mf, ks);
        #pragma unroll
        for (int ks = 0; ks < 2; ++ks)
            #pragma unroll
            for (int nf = 0; nf < 2; ++nf)
                #pragma unroll
                for (int mf = 0; mf < 4; ++mf)
                    acc[4 + mf][nf] = __builtin_amdgcn_mfma_f32_16x16x32_bf16(aF[mf][ks], bF[nf][ks], acc[4 + mf][nf], 0, 0, 0);

        // ---- phase 3: (A1,B1) ----
        if (st) STAGE_HALF(xpanel, t + 1, 1, &AL[cn][1][0]);
        gateB();
        #pragma unroll
        for (int ks = 0; ks < 2; ++ks)
            #pragma unroll
            for (int nf = 0; nf < 2; ++nf)
                #pragma unroll
                for (int mf = 0; mf < 4; ++mf)
                    acc[4 + mf][2 + nf] = __builtin_amdgcn_mfma_f32_16x16x32_bf16(aF[mf][ks], bF[2 + nf][ks], acc[4 + mf][2 + nf], 0, 0, 0);
    }
    #undef STAGE_HALF
    #undef RDA
    #undef RDB

    #pragma unroll
    for (int nf = 0; nf < 4; ++nf) {
        int col = colbase + ((nf < 2) ? wn * 32 + nf * 16 : 128 + wn * 32 + (nf - 2) * 16) + l15;
        float bv_ = bias[col] * wscale;
        #pragma unroll
        for (int mf = 0; mf < 8; ++mf) {
            int row0 = rowbase + ((mf < 4) ? wm * 64 + mf * 16 : 128 + wm * 64 + (mf - 4) * 16) + l4 * 4;
            #pragma unroll
            for (int r = 0; r < 4; ++r)
                out[(size_t)(row0 + r) * DD + col] = f2bf(acc[mf][nf][r] + bv_);
        }
    }
}

// ---------------------------------------------------------------------------
// Kernel 2: V transpose.  v[b][l][d] -> vt[b][d][l]  (bf16)
// ---------------------------------------------------------------------------
__global__ __launch_bounds__(256) void vtrans(const unsigned short* __restrict__ v,
                                              unsigned short* __restrict__ vt)
{
    __shared__ unsigned short T[64][72];
    const int lt = blockIdx.x, dt = blockIdx.y, b = blockIdx.z;
    const int t = threadIdx.x;
    const unsigned short* src = v + ((size_t)(b * LL + lt * 64)) * DD + dt * 64;
    #pragma unroll
    for (int it = 0; it < 2; ++it) {
        int r  = (t >> 3) + it * 32;
        int c0 = (t & 7) * 8;
        bf16x8 x = *(const bf16x8*)(src + (size_t)r * DD + c0);
        *(bf16x4*)&T[r][c0]     = (bf16x4){x[0], x[1], x[2], x[3]};
        *(bf16x4*)&T[r][c0 + 4] = (bf16x4){x[4], x[5], x[6], x[7]};
    }
    __syncthreads();
    unsigned short* dst = vt + ((size_t)(b * DD + dt * 64)) * LL + lt * 64;
    #pragma unroll
    for (int it = 0; it < 2; ++it) {
        int d  = (t >> 3) + it * 32;
        int c0 = (t & 7) * 8;
        bf16x8 o;
        #pragma unroll
        for (int e = 0; e < 8; ++e) o[e] = T[c0 + e][d];
        *(bf16x8*)(dst + (size_t)d * LL + c0) = o;
    }
}

// ---------------------------------------------------------------------------
// Kernel 3: flash attention v6 — attn3's compute paths with single-buffered
// K and V (LDS 70,144 B -> 2 INDEPENDENT blocks/CU; 2x228 VGPR <= 512/SIMD)
// and a 3-barrier counted-vmcnt schedule:
//   barA[vmcnt(8)]  : K(jt) landed (V(jt)'s 8 loads may still fly)
//   QK^T            : reads Kbuf
//   barB[syncthreads]: Kbuf free by all waves; vmcnt(0) -> V(jt) landed
//   STAGE_K(jt+1)   : flies during softmax+PV (~1.2K cyc)
//   softmax (mask from global, no mbias LDS)
//   PV              : reads Vbuf
//   barC[plain]     : Vbuf free
//   STAGE_V(jt+1)   : flies during barA-wait + QK of jt+1, plus partner-block
//                     compute covers any residue.
// Block mapping: qt=(bx>>4)&15, b=(bx&15)|(bx>>8)<<4 — bx and bx+256 (the
// likely co-resident pair on a CU) share qt -> equal-length concurrent blocks.
// ---------------------------------------------------------------------------
__global__ __launch_bounds__(256) void attn6(
    const unsigned short* __restrict__ qkv,
    const unsigned short* __restrict__ vt,
    const int* __restrict__ mask,
    float* __restrict__ outp)
{
    __shared__ __align__(16) unsigned short KtL[16384];    // [32 keys][512 d] = 32 KB
    __shared__ __align__(16) unsigned short VtL[16384];    // [512 d][32 keys] = 32 KB
    __shared__ __align__(16) unsigned short Pw[4][16][36]; // 4.5 KB; total 70,144 B

    const int bx = blockIdx.x;
    const int qt = (bx >> 4) & 15;
    const int b  = (bx & 15) | ((bx >> 8) << 4);

    const int tid = threadIdx.x, lane = tid & 63, w = tid >> 6;
    const int l15 = lane & 15, l4 = lane >> 4;
    const int lsw = lane * 16;

    const unsigned short* q = qkv;
    const unsigned short* k = qkv + MAT;
    const char* kb  = (const char*)k + ((size_t)b * LL) * DD * 2;   // row = 1024 B
    const char* vtb = (const char*)vt + ((size_t)b * DD) * LL * 2;  // row = 2048 B
    const int* mp = mask + b * LL;

    // persistent Q A-frags (16 global loads; drained before first QK use)
    bf16x8 qf[16];
    {
        const unsigned short* qp = q + ((size_t)(b * LL + qt * 64 + w * 16 + l15)) * DD + l4 * 8;
        #pragma unroll
        for (int ks = 0; ks < 16; ++ks)
            qf[ks] = *(const bf16x8*)(qp + ks * 32);
    }

    f32x4 oacc[32];
    #pragma unroll
    for (int n = 0; n < 32; ++n) oacc[n] = (f32x4){0.f, 0.f, 0.f, 0.f};
    float mrow[4] = {-1e30f, -1e30f, -1e30f, -1e30f};
    float lrow[4] = {0.f, 0.f, 0.f, 0.f};

    const int jtmax = 2 * qt + 1;

    // 8 wave-instructions each (per wave): K then V, counted by barA/barB
    #define STAGE_K6(JT) do {                                                   \
        const char* kt = kb + ((size_t)(JT) << 15);                             \
        _Pragma("unroll")                                                       \
        for (int i2 = 0; i2 < 8; ++i2) {                                        \
            int row = i2 * 4 + w;                                               \
            GLOAD_LDS16(kt + (row << 10) + (lsw ^ ((row & 7) << 4)),            \
                        (char*)KtL + (row << 10));                              \
        }                                                                       \
    } while (0)

    #define STAGE_V6(JT) do {                                                   \
        const char* vtj = vtb + ((size_t)(JT) << 6);                            \
        _Pragma("unroll")                                                       \
        for (int i2 = 0; i2 < 8; ++i2) {                                        \
            int c0 = i2 * 256 + w * 64;                                         \
            int c  = c0 + lane;                                                 \
            GLOAD_LDS16(vtj + ((size_t)(c >> 2) << 11) + ((c & 3) << 4),        \
                        (char*)VtL + c0 * 16);                                  \
        }                                                                       \
    } while (0)

    STAGE_K6(0);
    STAGE_V6(0);

    const int swz = (l15 & 7) << 4;

    for (int jt = 0; jt <= jtmax; ++jt) {
        gate8();   // barA: own 8 K-loads (oldest) done; V's 8 may still fly

        // ---- QK^T: S[16 own rows][32 keys] from swizzled K LDS ----
        f32x4 sacc[2];
        sacc[0] = (f32x4){0.f, 0.f, 0.f, 0.f};
        sacc[1] = (f32x4){0.f, 0.f, 0.f, 0.f};
        #pragma unroll
        for (int ks = 0; ks < 16; ++ks) {
            int coloff = ((ks << 6) + (l4 << 4)) ^ swz;
            #pragma unroll
            for (int nf = 0; nf < 2; ++nf) {
                const bf16x8 kf = *(const bf16x8*)((const char*)KtL + ((nf * 16 + l15) << 10) + coloff);
                sacc[nf] = __builtin_amdgcn_mfma_f32_16x16x32_bf16(qf[ks], kf, sacc[nf], 0, 0, 0);
            }
        }

        __builtin_amdgcn_sched_barrier(0);
        __syncthreads();   // barB: Kbuf free by all; vmcnt(0) -> V(jt) landed
        __builtin_amdgcn_sched_barrier(0);
        if (jt < jtmax) STAGE_K6(jt + 1);

        // ---- mask (from global) + causal + online softmax (in-register) ----
        const bool diag = (jt >= 2 * qt);
        float mb0 = mp[jt * 32 + l15]      ? 0.0f : -1e30f;
        float mb1 = mp[jt * 32 + 16 + l15] ? 0.0f : -1e30f;
        float s[2][4];
        #pragma unroll
        for (int nf = 0; nf < 2; ++nf) {
            float bb_ = nf ? mb1 : mb0;
            #pragma unroll
            for (int r = 0; r < 4; ++r) {
                float val = sacc[nf][r] + bb_;
                if (diag) {
                    int gi = qt * 64 + w * 16 + l4 * 4 + r;
                    int gj = jt * 32 + nf * 16 + l15;
                    val = (gj <= gi) ? val : -3e38f;
                }
                s[nf][r] = val;
            }
        }
        float pm[4];
        #pragma unroll
        for (int r = 0; r < 4; ++r) {
            float mx = fmaxf(s[0][r], s[1][r]);
            mx = fmaxf(mx, __shfl_xor(mx, 1));
            mx = fmaxf(mx, __shfl_xor(mx, 2));
            mx = fmaxf(mx, __shfl_xor(mx, 4));
            mx = fmaxf(mx, __shfl_xor(mx, 8));
            pm[r] = mx;
        }
        bool need = false;
        #pragma unroll
        for (int r = 0; r < 4; ++r) need |= (pm[r] - mrow[r] > 8.0f);
        if (__any(need)) {
            #pragma unroll
            for (int r = 0; r < 4; ++r) {
                float mn = fmaxf(mrow[r], pm[r]);
                float corr = __expf(mrow[r] - mn);
                mrow[r] = mn;
                lrow[r] *= corr;
                #pragma unroll
                for (int n = 0; n < 32; ++n) oacc[n][r] *= corr;
            }
        }
        #pragma unroll
        for (int r = 0; r < 4; ++r) {
            float ls = 0.f;
            #pragma unroll
            for (int nf = 0; nf < 2; ++nf) {
                float p = __expf(s[nf][r] - mrow[r]);
                ls += p;
                Pw[w][l4 * 4 + r][nf * 16 + l15] = f2bf(p);
            }
            ls += __shfl_xor(ls, 1);
            ls += __shfl_xor(ls, 2);
            ls += __shfl_xor(ls, 4);
            ls += __shfl_xor(ls, 8);
            lrow[r] += ls;
        }

        // ---- PV: O[16 rows][512] += P[16][32] * V[32][512] (V from LDS) ----
        const bf16x8 pa = *(const bf16x8*)&Pw[w][l15][l4 * 8];
        #pragma unroll
        for (int n = 0; n < 32; ++n) {
            const bf16x8 vb_ = *(const bf16x8*)((const char*)VtL + ((n * 16 + l15) << 6) + (l4 << 4));
            oacc[n] = __builtin_amdgcn_mfma_f32_16x16x32_bf16(pa, vb_, oacc[n], 0, 0, 0);
        }

        if (jt < jtmax) {
            gateB();          // barC: Vbuf free by all (ds_reads consumed pre-barrier)
            STAGE_V6(jt + 1);
        }
    }

    // ---- epilogue: relu(O / l) ----
    float inv[4];
    #pragma unroll
    for (int r = 0; r < 4; ++r) inv[r] = 1.0f / lrow[r];
    float* op = outp + ((size_t)(b * LL + qt * 64 + w * 16 + l4 * 4)) * DD + l15;
    #pragma unroll
    for (int n = 0; n < 32; ++n)
        #pragma unroll
        for (int r = 0; r < 4; ++r)
            op[(size_t)r * DD + n * 16] = fmaxf(oacc[n][r] * inv[r], 0.f);
    #undef STAGE_K6
    #undef STAGE_V6
}

extern "C" void kernel_launch(void* const* d_in, const int* in_sizes, int n_in,
                              void* d_out, int out_size, void* d_ws, size_t ws_size,
                              hipStream_t stream) {
    const float* x  = (const float*)d_in[0];
    const float* Wq = (const float*)d_in[1];
    const float* bq = (const float*)d_in[2];
    const float* Wk = (const float*)d_in[3];
    const float* bk = (const float*)d_in[4];
    const float* Wv = (const float*)d_in[5];
    const float* bv = (const float*)d_in[6];
    const int* mask = (const int*)d_in[7];

    unsigned short* qkv = (unsigned short*)d_ws;          // q|k|v bf16
    unsigned short* v   = qkv + 2 * MAT;
    unsigned short* vtp = qkv + 3 * MAT;                  // vt region
    unsigned short* Wb  = vtp;                            // parked, overwritten by vtrans
    unsigned short* xb  = (unsigned short*)d_out;         // x bf16 scratch
    float* out = (float*)d_out;

    cast_x<<<16384, 256, 0, stream>>>(x, xb);
    cast_w<<<768, 256, 0, stream>>>(Wq, Wk, Wv, Wb);
    qkv_proj4<<<dim3(256, 3), 512, 0, stream>>>(xb, Wb, bq, bk, bv, qkv);
    vtrans<<<dim3(16, 8, 32), 256, 0, stream>>>(v, vtp);
    attn6<<<dim3(512), 256, 0, stream>>>(qkv, vtp, mask, out);
}

// Round 10
// 277.498 us; speedup vs baseline: 1.2105x; 1.2105x over previous
//
#include <hip/hip_runtime.h>
#include <hip/hip_bf16.h>
#include <stdint.h>

#define DM 1024   // d_model
#define DD 512    // d (proj out / head dim)
#define BB 32     // batch
#define LL 1024   // seq len
#define SCALE 0.04419417382415922f  // 1/sqrt(512)
#define MAT ((size_t)BB * LL * DD)  // elems per q/k/v matrix

typedef float f32x4 __attribute__((ext_vector_type(4)));
typedef short bf16x8 __attribute__((ext_vector_type(8)));
typedef short bf16x4 __attribute__((ext_vector_type(4)));

__device__ inline unsigned short f2bf(float f) {
    union { float f; uint32_t u; } v; v.f = f;
    uint32_t r = v.u + 0x7fffu + ((v.u >> 16) & 1u);
    return (unsigned short)(r >> 16);
}
__device__ inline float bf2f(unsigned short u) {
    union { uint32_t u; float f; } v; v.u = ((uint32_t)u) << 16;
    return v.f;
}

__device__ inline bf16x4 cvt4(f32x4 a, float s) {
    bf16x4 r;
    r[0] = (short)f2bf(a[0] * s);
    r[1] = (short)f2bf(a[1] * s);
    r[2] = (short)f2bf(a[2] * s);
    r[3] = (short)f2bf(a[3] * s);
    return r;
}

#define GLOAD_LDS16(gsrc, ldst) \
    __builtin_amdgcn_global_load_lds((const __attribute__((address_space(1))) unsigned int*)(gsrc), \
        (__attribute__((address_space(3))) unsigned int*)(ldst), 16, 0, 0)

__device__ inline void publish_barrier() {
    asm volatile("s_waitcnt vmcnt(0)" ::: "memory");
    __builtin_amdgcn_sched_barrier(0);
    __builtin_amdgcn_s_barrier();
    __builtin_amdgcn_sched_barrier(0);
}
__device__ inline void gate6() {
    asm volatile("s_waitcnt vmcnt(6)" ::: "memory");
    __builtin_amdgcn_sched_barrier(0);
    __builtin_amdgcn_s_barrier();
    __builtin_amdgcn_sched_barrier(0);
}
__device__ inline void gate4() {
    asm volatile("s_waitcnt vmcnt(4)" ::: "memory");
    __builtin_amdgcn_sched_barrier(0);
    __builtin_amdgcn_s_barrier();
    __builtin_amdgcn_sched_barrier(0);
}
__device__ inline void gate2() {
    asm volatile("s_waitcnt vmcnt(2)" ::: "memory");
    __builtin_amdgcn_sched_barrier(0);
    __builtin_amdgcn_s_barrier();
    __builtin_amdgcn_sched_barrier(0);
}
__device__ inline void gate0() {
    asm volatile("s_waitcnt vmcnt(0)" ::: "memory");
    __builtin_amdgcn_sched_barrier(0);
    __builtin_amdgcn_s_barrier();
    __builtin_amdgcn_sched_barrier(0);
}
__device__ inline void gateB() {
    __builtin_amdgcn_sched_barrier(0);
    __builtin_amdgcn_s_barrier();
    __builtin_amdgcn_sched_barrier(0);
}

// ---------------------------------------------------------------------------
// Kernel 0a: cast x fp32 -> bf16 (dest: d_out reused as scratch; dead by S)
// ---------------------------------------------------------------------------
__global__ __launch_bounds__(256) void cast_x(const float* __restrict__ x,
                                              unsigned short* __restrict__ xb)
{
    size_t idx = (size_t)blockIdx.x * 256 + threadIdx.x;
    size_t base = idx * 8;
    f32x4 a = *(const f32x4*)(x + base);
    f32x4 b = *(const f32x4*)(x + base + 4);
    bf16x4 lo = cvt4(a, 1.0f), hi = cvt4(b, 1.0f);
    bf16x8 o = {lo[0], lo[1], lo[2], lo[3], hi[0], hi[1], hi[2], hi[3]};
    *(bf16x8*)(xb + base) = o;
}

// ---------------------------------------------------------------------------
// Kernel 0b: cast Wq/Wk/Wv fp32 -> bf16 (Wq pre-scaled by 1/sqrt(D))
// ---------------------------------------------------------------------------
__global__ __launch_bounds__(256) void cast_w(const float* __restrict__ Wq,
                                              const float* __restrict__ Wk,
                                              const float* __restrict__ Wv,
                                              unsigned short* __restrict__ Wb)
{
    size_t idx = (size_t)blockIdx.x * 256 + threadIdx.x;   // 0..196607
    int o = (int)(idx >> 16);
    size_t rem = idx & 65535;
    const float* W = (o == 0) ? Wq : (o == 1) ? Wk : Wv;
    float s = (o == 0) ? SCALE : 1.0f;
    size_t base = rem * 8;
    f32x4 a = *(const f32x4*)(W + base);
    f32x4 b = *(const f32x4*)(W + base + 4);
    bf16x4 lo = cvt4(a, s), hi = cvt4(b, s);
    bf16x8 out = {lo[0], lo[1], lo[2], lo[3], hi[0], hi[1], hi[2], hi[3]};
    *(bf16x8*)(Wb + (size_t)o * 524288 + base) = out;
}

// ---------------------------------------------------------------------------
// Kernel 1: q/k/v projection v4 (unchanged from round 8 — 8-phase 256x256).
// ---------------------------------------------------------------------------
__global__ __launch_bounds__(512, 2) void qkv_proj4(
    const unsigned short* __restrict__ xb,
    const unsigned short* __restrict__ Wb,
    const float* __restrict__ bq, const float* __restrict__ bk, const float* __restrict__ bv,
    unsigned short* __restrict__ qkv)
{
    __shared__ __align__(16) unsigned short AL[2][2][8192];
    __shared__ __align__(16) unsigned short BL[2][2][8192];

    const int o = blockIdx.y;
    const float* bias = (o == 0) ? bq : (o == 1) ? bk : bv;
    const float wscale = (o == 0) ? SCALE : 1.0f;
    const unsigned short* W = Wb + (size_t)o * 524288;
    unsigned short* out = qkv + (size_t)o * MAT;

    int wg = blockIdx.x;
    wg = (wg & 7) * 32 + (wg >> 3);
    const int mt = wg >> 1, nt = wg & 1;
    const int rowbase = mt * 256;
    const int colbase = nt * 256;

    const int tid  = threadIdx.x;
    const int lane = tid & 63;
    const int w    = tid >> 6;
    const int wm   = w >> 2;
    const int wn   = w & 3;
    const int l15  = lane & 15, l4 = lane >> 4;
    const int rxor = l15 & 7;

    const int r8   = lane >> 3;
    const int swch = (lane & 7) ^ r8;

    const char* xpanel = (const char*)(xb + (size_t)rowbase * DM);
    const char* wpanel = (const char*)(W  + (size_t)colbase * DM);

    #define STAGE_HALF(panel, T, H, slot) do {                                   \
        _Pragma("unroll")                                                        \
        for (int i2 = 0; i2 < 2; ++i2) {                                         \
            int grp = i2 * 8 + w;                                                \
            GLOAD_LDS16((panel) + ((size_t)((H) * 128 + grp * 8 + r8) * 2048)    \
                            + (size_t)(T) * 128 + swch * 16,                     \
                        (char*)(slot) + grp * 1024);                             \
        }                                                                        \
    } while (0)

    #define RDA(base, mf4, ks) (*(const bf16x8*)((base) + (wm * 64 + (mf4) * 16 + l15) * 128 \
                            + ((((ks) * 4 + l4) ^ rxor) << 4)))
    #define RDB(base, nfl, ks) (*(const bf16x8*)((base) + (wn * 32 + (nfl) * 16 + l15) * 128 \
                            + ((((ks) * 4 + l4) ^ rxor) << 4)))

    f32x4 acc[8][4];
    #pragma unroll
    for (int i = 0; i < 8; ++i)
        #pragma unroll
        for (int j = 0; j < 4; ++j)
            acc[i][j] = (f32x4){0.f, 0.f, 0.f, 0.f};

    bf16x8 aF[4][2], bF[4][2];

    STAGE_HALF(xpanel, 0, 0, &AL[0][0][0]);
    STAGE_HALF(wpanel, 0, 0, &BL[0][0][0]);
    STAGE_HALF(wpanel, 0, 1, &BL[0][1][0]);
    STAGE_HALF(xpanel, 0, 1, &AL[0][1][0]);

    for (int t = 0; t < 16; ++t) {
        const int c = t & 1, cn = c ^ 1;
        const char* A0b = (const char*)&AL[c][0][0];
        const char* A1b = (const char*)&AL[c][1][0];
        const char* B0b = (const char*)&BL[c][0][0];
        const char* B1b = (const char*)&BL[c][1][0];
        const bool st = (t < 15);

        if (st) { STAGE_HALF(xpanel, t + 1, 0, &AL[cn][0][0]); gate6(); } else gate4();
        #pragma unroll
        for (int ks = 0; ks < 2; ++ks) {
            #pragma unroll
            for (int mf = 0; mf < 4; ++mf) aF[mf][ks] = RDA(A0b, mf, ks);
            bF[0][ks] = RDB(B0b, 0, ks);
            bF[1][ks] = RDB(B0b, 1, ks);
        }
        #pragma unroll
        for (int ks = 0; ks < 2; ++ks)
            #pragma unroll
            for (int nf = 0; nf < 2; ++nf)
                #pragma unroll
                for (int mf = 0; mf < 4; ++mf)
                    acc[mf][nf] = __builtin_amdgcn_mfma_f32_16x16x32_bf16(aF[mf][ks], bF[nf][ks], acc[mf][nf], 0, 0, 0);

        if (st) { STAGE_HALF(wpanel, t + 1, 0, &BL[cn][0][0]); gate6(); } else gate2();
        #pragma unroll
        for (int ks = 0; ks < 2; ++ks) {
            bF[2][ks] = RDB(B1b, 0, ks);
            bF[3][ks] = RDB(B1b, 1, ks);
        }
        #pragma unroll
        for (int ks = 0; ks < 2; ++ks)
            #pragma unroll
            for (int nf = 0; nf < 2; ++nf)
                #pragma unroll
                for (int mf = 0; mf < 4; ++mf)
                    acc[mf][2 + nf] = __builtin_amdgcn_mfma_f32_16x16x32_bf16(aF[mf][ks], bF[2 + nf][ks], acc[mf][2 + nf], 0, 0, 0);

        if (st) { STAGE_HALF(wpanel, t + 1, 1, &BL[cn][1][0]); gate6(); } else gate0();
        #pragma unroll
        for (int ks = 0; ks < 2; ++ks)
            #pragma unroll
            for (int mf = 0; mf < 4; ++mf) aF[mf][ks] = RDA(A1b, mf, ks);
        #pragma unroll
        for (int ks = 0; ks < 2; ++ks)
            #pragma unroll
            for (int nf = 0; nf < 2; ++nf)
                #pragma unroll
                for (int mf = 0; mf < 4; ++mf)
                    acc[4 + mf][nf] = __builtin_amdgcn_mfma_f32_16x16x32_bf16(aF[mf][ks], bF[nf][ks], acc[4 + mf][nf], 0, 0, 0);

        if (st) STAGE_HALF(xpanel, t + 1, 1, &AL[cn][1][0]);
        gateB();
        #pragma unroll
        for (int ks = 0; ks < 2; ++ks)
            #pragma unroll
            for (int nf = 0; nf < 2; ++nf)
                #pragma unroll
                for (int mf = 0; mf < 4; ++mf)
                    acc[4 + mf][2 + nf] = __builtin_amdgcn_mfma_f32_16x16x32_bf16(aF[mf][ks], bF[2 + nf][ks], acc[4 + mf][2 + nf], 0, 0, 0);
    }
    #undef STAGE_HALF
    #undef RDA
    #undef RDB

    #pragma unroll
    for (int nf = 0; nf < 4; ++nf) {
        int col = colbase + ((nf < 2) ? wn * 32 + nf * 16 : 128 + wn * 32 + (nf - 2) * 16) + l15;
        float bv_ = bias[col] * wscale;
        #pragma unroll
        for (int mf = 0; mf < 8; ++mf) {
            int row0 = rowbase + ((mf < 4) ? wm * 64 + mf * 16 : 128 + wm * 64 + (mf - 4) * 16) + l4 * 4;
            #pragma unroll
            for (int r = 0; r < 4; ++r)
                out[(size_t)(row0 + r) * DD + col] = f2bf(acc[mf][nf][r] + bv_);
        }
    }
}

// ---------------------------------------------------------------------------
// Kernel 2: V transpose.  v[b][l][d] -> vt[b][d][l]  (bf16)
// ---------------------------------------------------------------------------
__global__ __launch_bounds__(256) void vtrans(const unsigned short* __restrict__ v,
                                              unsigned short* __restrict__ vt)
{
    __shared__ unsigned short T[64][72];
    const int lt = blockIdx.x, dt = blockIdx.y, b = blockIdx.z;
    const int t = threadIdx.x;
    const unsigned short* src = v + ((size_t)(b * LL + lt * 64)) * DD + dt * 64;
    #pragma unroll
    for (int it = 0; it < 2; ++it) {
        int r  = (t >> 3) + it * 32;
        int c0 = (t & 7) * 8;
        bf16x8 x = *(const bf16x8*)(src + (size_t)r * DD + c0);
        *(bf16x4*)&T[r][c0]     = (bf16x4){x[0], x[1], x[2], x[3]};
        *(bf16x4*)&T[r][c0 + 4] = (bf16x4){x[4], x[5], x[6], x[7]};
    }
    __syncthreads();
    unsigned short* dst = vt + ((size_t)(b * DD + dt * 64)) * LL + lt * 64;
    #pragma unroll
    for (int it = 0; it < 2; ++it) {
        int d  = (t >> 3) + it * 32;
        int c0 = (t & 7) * 8;
        bf16x8 o;
        #pragma unroll
        for (int e = 0; e < 8; ++e) o[e] = T[c0 + e][d];
        *(bf16x8*)(dst + (size_t)d * LL + c0) = o;
    }
}

// ---------------------------------------------------------------------------
// Kernel 3: S = q . k^T, lower-triangle 128x128 tiles only (proj3 clone:
// BK=64, dbuf LDS, gload_lds + both-sides XOR swizzle, 1 barrier/K-tile,
// 2 blocks/CU). S bf16 [b][1024][1024] -> d_out (xb dead).
// ---------------------------------------------------------------------------
__global__ __launch_bounds__(256, 2) void sgemm_qk(
    const unsigned short* __restrict__ qkv,
    unsigned short* __restrict__ S)
{
    __shared__ __align__(16) unsigned short At[2][8192];
    __shared__ __align__(16) unsigned short Bt[2][8192];

    int wg = blockIdx.x;                       // 1152 = 8 * 144, chunked XCD swizzle
    wg = (wg & 7) * 144 + (wg >> 3);
    const int b = wg / 36;
    const int t36 = wg % 36;
    int mt = 0, accq = 0;
    while (accq + mt + 1 <= t36) { ++mt; accq += mt; }
    const int nt = t36 - accq;                 // nt <= mt (lower triangle)

    const int tid  = threadIdx.x;
    const int lane = tid & 63;
    const int w    = tid >> 6;
    const int wr   = (w >> 1) * 64;
    const int wc   = (w & 1) * 64;
    const int l15  = lane & 15, l4 = lane >> 4;

    const int r8   = lane >> 3;
    const int swch = (lane & 7) ^ r8;

    const unsigned short* q = qkv;
    const unsigned short* k = qkv + MAT;
    const char* apanel = (const char*)(q + ((size_t)(b * LL) + mt * 128) * DD);  // row=1024B
    const char* bpanel = (const char*)(k + ((size_t)(b * LL) + nt * 128) * DD);

    f32x4 acc[4][4];
    #pragma unroll
    for (int i = 0; i < 4; ++i)
        #pragma unroll
        for (int j = 0; j < 4; ++j)
            acc[i][j] = (f32x4){0.f, 0.f, 0.f, 0.f};

    #define STAGE_QK(KK, BUF) do {                                               \
        _Pragma("unroll")                                                        \
        for (int i2 = 0; i2 < 4; ++i2) {                                         \
            int grp = i2 * 4 + w;                                                \
            size_t rowoff = (size_t)(grp * 8 + r8) * 1024 + (KK) * 2 + swch * 16;\
            GLOAD_LDS16(apanel + rowoff, (char*)&At[BUF][0] + grp * 1024);       \
            GLOAD_LDS16(bpanel + rowoff, (char*)&Bt[BUF][0] + grp * 1024);       \
        }                                                                        \
    } while (0)

    STAGE_QK(0, 0);
    __syncthreads();

    for (int t = 0; t < 8; ++t) {
        const int cur = t & 1;
        if (t < 7) STAGE_QK((t + 1) * 64, cur ^ 1);

        const char* Ab = (const char*)&At[cur][0];
        const char* Bb = (const char*)&Bt[cur][0];
        #pragma unroll
        for (int ks = 0; ks < 2; ++ks) {
            bf16x8 af[4], bf_[4];
            const int ch = (ks * 4 + l4) ^ (l15 & 7);
            #pragma unroll
            for (int m = 0; m < 4; ++m)
                af[m] = *(const bf16x8*)(Ab + (wr + m * 16 + l15) * 128 + (ch << 4));
            #pragma unroll
            for (int n = 0; n < 4; ++n)
                bf_[n] = *(const bf16x8*)(Bb + (wc + n * 16 + l15) * 128 + (ch << 4));
            #pragma unroll
            for (int n = 0; n < 4; ++n)
                #pragma unroll
                for (int m = 0; m < 4; ++m)
                    acc[m][n] = __builtin_amdgcn_mfma_f32_16x16x32_bf16(af[m], bf_[n], acc[m][n], 0, 0, 0);
        }

        if (t < 7) publish_barrier();
    }
    #undef STAGE_QK

    // epilogue: S[b][mt*128 + row][nt*128 + col] bf16 (row stride 1024 elems)
    unsigned short* sp = S + ((size_t)(b * LL) + mt * 128) * LL + nt * 128;
    #pragma unroll
    for (int n = 0; n < 4; ++n) {
        int col = wc + n * 16 + l15;
        #pragma unroll
        for (int m = 0; m < 4; ++m) {
            int row0 = wr + m * 16 + l4 * 4;
            #pragma unroll
            for (int r = 0; r < 4; ++r)
                sp[(size_t)(row0 + r) * LL + col] = f2bf(acc[m][n][r]);
        }
    }
}

// ---------------------------------------------------------------------------
// Kernel 4: row softmax with causal + padding mask.
// P[b][i][j] = softmax_j<=i(S[b][i][j] + maskbias[j]); zeros for j > i.
// Block = (row-chunk of 128, b), 4 waves; wave handles rows i*4+w (length-
// interleaved for balance). Lane owns 16 cols; loads skipped above diagonal.
// ---------------------------------------------------------------------------
__global__ __launch_bounds__(256) void softmax_rows(
    const unsigned short* __restrict__ S,
    const int* __restrict__ mask,
    unsigned short* __restrict__ P)
{
    __shared__ float mbias[1024];
    const int rc = blockIdx.x, b = blockIdx.y;
    const int tid = threadIdx.x, lane = tid & 63, w = tid >> 6;

    {
        const int* mp = mask + b * LL;
        #pragma unroll
        for (int j = 0; j < 4; ++j)
            mbias[tid * 4 + j] = mp[tid * 4 + j] ? 0.0f : -1e30f;
    }
    __syncthreads();

    const int j0 = lane * 16;
    for (int i = 0; i < 32; ++i) {
        const int r = rc * 128 + i * 4 + w;
        const unsigned short* srow = S + ((size_t)(b * LL) + r) * LL;

        bf16x8 v0 = {0,0,0,0,0,0,0,0}, v1 = {0,0,0,0,0,0,0,0};
        if (j0 <= r)     v0 = *(const bf16x8*)(srow + j0);
        if (j0 + 8 <= r) v1 = *(const bf16x8*)(srow + j0 + 8);

        float s[16];
        #pragma unroll
        for (int e = 0; e < 8; ++e) {
            int j = j0 + e;
            s[e]     = (j <= r)     ? bf2f((unsigned short)v0[e]) + mbias[j]     : -3e38f;
            s[8 + e] = (j + 8 <= r) ? bf2f((unsigned short)v1[e]) + mbias[j + 8] : -3e38f;
        }
        float mx = s[0];
        #pragma unroll
        for (int e = 1; e < 16; ++e) mx = fmaxf(mx, s[e]);
        mx = fmaxf(mx, __shfl_xor(mx, 1));
        mx = fmaxf(mx, __shfl_xor(mx, 2));
        mx = fmaxf(mx, __shfl_xor(mx, 4));
        mx = fmaxf(mx, __shfl_xor(mx, 8));
        mx = fmaxf(mx, __shfl_xor(mx, 16));
        mx = fmaxf(mx, __shfl_xor(mx, 32));

        float p[16], ls = 0.f;
        #pragma unroll
        for (int e = 0; e < 16; ++e) { p[e] = __expf(s[e] - mx); ls += p[e]; }
        ls += __shfl_xor(ls, 1);
        ls += __shfl_xor(ls, 2);
        ls += __shfl_xor(ls, 4);
        ls += __shfl_xor(ls, 8);
        ls += __shfl_xor(ls, 16);
        ls += __shfl_xor(ls, 32);
        const float inv = 1.0f / ls;

        bf16x8 o0, o1;
        #pragma unroll
        for (int e = 0; e < 8; ++e) {
            o0[e] = (short)f2bf(p[e] * inv);
            o1[e] = (short)f2bf(p[8 + e] * inv);
        }
        unsigned short* prow = P + ((size_t)(b * LL) + r) * LL;
        *(bf16x8*)(prow + j0)     = o0;
        *(bf16x8*)(prow + j0 + 8) = o1;
    }
}

// ---------------------------------------------------------------------------
// Kernel 5: O = relu(P . V) via vt ([d][key], key-contiguous). proj3 clone,
// variable K-depth per row-tile (causal truncation), heavy-first ordering.
// Output fp32 -> d_out (S dead).
// ---------------------------------------------------------------------------
__global__ __launch_bounds__(256, 2) void pv_gemm(
    const unsigned short* __restrict__ P,
    const unsigned short* __restrict__ vt,
    float* __restrict__ outp)
{
    __shared__ __align__(16) unsigned short At[2][8192];
    __shared__ __align__(16) unsigned short Bt[2][8192];

    int wg = blockIdx.x;                       // 1024 = 8 * 128, chunked XCD swizzle
    wg = (wg & 7) * 128 + (wg >> 3);
    const int b  = wg >> 5;
    const int rr = wg & 31;
    const int rt = 7 - (rr >> 2);              // heavy (deep-K) row-tiles first
    const int ct = rr & 3;

    const int tid  = threadIdx.x;
    const int lane = tid & 63;
    const int w    = tid >> 6;
    const int wr   = (w >> 1) * 64;
    const int wc   = (w & 1) * 64;
    const int l15  = lane & 15, l4 = lane >> 4;

    const int r8   = lane >> 3;
    const int swch = (lane & 7) ^ r8;

    const char* apanel = (const char*)(P  + ((size_t)(b * LL) + rt * 128) * LL);  // row=2048B
    const char* bpanel = (const char*)(vt + ((size_t)(b * DD) + ct * 128) * LL);  // row=2048B

    const int NT = (rt + 1) * 2;               // 64-key tiles (keys <= (rt+1)*128)

    f32x4 acc[4][4];
    #pragma unroll
    for (int i = 0; i < 4; ++i)
        #pragma unroll
        for (int j = 0; j < 4; ++j)
            acc[i][j] = (f32x4){0.f, 0.f, 0.f, 0.f};

    #define STAGE_PV(KK, BUF) do {                                               \
        _Pragma("unroll")                                                        \
        for (int i2 = 0; i2 < 4; ++i2) {                                         \
            int grp = i2 * 4 + w;                                                \
            size_t rowoff = (size_t)(grp * 8 + r8) * 2048 + (KK) * 2 + swch * 16;\
            GLOAD_LDS16(apanel + rowoff, (char*)&At[BUF][0] + grp * 1024);       \
            GLOAD_LDS16(bpanel + rowoff, (char*)&Bt[BUF][0] + grp * 1024);       \
        }                                                                        \
    } while (0)

    STAGE_PV(0, 0);
    __syncthreads();

    for (int t = 0; t < NT; ++t) {
        const int cur = t & 1;
        if (t < NT - 1) STAGE_PV((t + 1) * 64, cur ^ 1);

        const char* Ab = (const char*)&At[cur][0];
        const char* Bb = (const char*)&Bt[cur][0];
        #pragma unroll
        for (int ks = 0; ks < 2; ++ks) {
            bf16x8 af[4], bf_[4];
            const int ch = (ks * 4 + l4) ^ (l15 & 7);
            #pragma unroll
            for (int m = 0; m < 4; ++m)
                af[m] = *(const bf16x8*)(Ab + (wr + m * 16 + l15) * 128 + (ch << 4));
            #pragma unroll
            for (int n = 0; n < 4; ++n)
                bf_[n] = *(const bf16x8*)(Bb + (wc + n * 16 + l15) * 128 + (ch << 4));
            #pragma unroll
            for (int n = 0; n < 4; ++n)
                #pragma unroll
                for (int m = 0; m < 4; ++m)
                    acc[m][n] = __builtin_amdgcn_mfma_f32_16x16x32_bf16(af[m], bf_[n], acc[m][n], 0, 0, 0);
        }

        if (t < NT - 1) publish_barrier();
    }
    #undef STAGE_PV

    // epilogue: relu, fp32; O[b][rt*128+row][ct*128+col]
    float* op = outp + ((size_t)(b * LL) + rt * 128) * DD + ct * 128;
    #pragma unroll
    for (int n = 0; n < 4; ++n) {
        int col = wc + n * 16 + l15;
        #pragma unroll
        for (int m = 0; m < 4; ++m) {
            int row0 = wr + m * 16 + l4 * 4;
            #pragma unroll
            for (int r = 0; r < 4; ++r)
                op[(size_t)(row0 + r) * DD + col] = fmaxf(acc[m][n][r], 0.f);
        }
    }
}

extern "C" void kernel_launch(void* const* d_in, const int* in_sizes, int n_in,
                              void* d_out, int out_size, void* d_ws, size_t ws_size,
                              hipStream_t stream) {
    const float* x  = (const float*)d_in[0];
    const float* Wq = (const float*)d_in[1];
    const float* bq = (const float*)d_in[2];
    const float* Wk = (const float*)d_in[3];
    const float* bk = (const float*)d_in[4];
    const float* Wv = (const float*)d_in[5];
    const float* bv = (const float*)d_in[6];
    const int* mask = (const int*)d_in[7];

    unsigned short* qkv = (unsigned short*)d_ws;          // q|k|v bf16 (3 x 32MB)
    unsigned short* v   = qkv + 2 * MAT;
    unsigned short* vtp = qkv + 3 * MAT;                  // vt region (32MB)
    unsigned short* Wb  = vtp;                            // parked, overwritten by vtrans
    unsigned short* xb  = (unsigned short*)d_out;         // x bf16 (64MB), dead after proj
    unsigned short* S   = (unsigned short*)d_out;         // S bf16 (64MB), overwrites xb
    unsigned short* Pp  = qkv;                            // P bf16 (64MB) over q+k (dead)
    float* out = (float*)d_out;                           // final O overwrites S

    cast_x<<<16384, 256, 0, stream>>>(x, xb);
    cast_w<<<768, 256, 0, stream>>>(Wq, Wk, Wv, Wb);
    qkv_proj4<<<dim3(256, 3), 512, 0, stream>>>(xb, Wb, bq, bk, bv, qkv);
    vtrans<<<dim3(16, 8, 32), 256, 0, stream>>>(v, vtp);
    sgemm_qk<<<dim3(1152), 256, 0, stream>>>(qkv, S);
    softmax_rows<<<dim3(8, 32), 256, 0, stream>>>(S, mask, Pp);
    pv_gemm<<<dim3(1024), 256, 0, stream>>>(Pp, vtp, out);
}